// Round 1
// baseline (365.051 us; speedup 1.0000x reference)
//
#include <hip/hip_runtime.h>

// ModernBertAttention fused pipeline, bf16 MFMA (16x16x32), fp32 I/O.
// B=4 S=2048 H=1024 NH=16 D=64.

typedef __bf16 bf16x8 __attribute__((ext_vector_type(8)));
typedef float f32x4 __attribute__((ext_vector_type(4)));
typedef unsigned short u16x8 __attribute__((ext_vector_type(8)));
typedef const __attribute__((address_space(1))) void* gptr_t;
typedef __attribute__((address_space(3))) void* lptr_t;

__device__ __forceinline__ unsigned short f2bf(float f) {
  union { float f; unsigned u; } v; v.f = f;
  unsigned r = (v.u + 0x7fffu + ((v.u >> 16) & 1u)) >> 16;  // RNE
  return (unsigned short)r;
}

__device__ __forceinline__ void gld16(const void* g, void* l) {
  __builtin_amdgcn_global_load_lds((gptr_t)g, (lptr_t)l, 16, 0, 0);
}

// f32 -> bf16, 8 elems/thread
__global__ __launch_bounds__(256) void cvt_bf16(const float* __restrict__ src,
                                                unsigned short* __restrict__ dst,
                                                int n8) {
  int i = blockIdx.x * 256 + threadIdx.x;
  if (i >= n8) return;
  const float4* s = (const float4*)src;
  float4 a = s[(size_t)i * 2], b = s[(size_t)i * 2 + 1];
  u16x8 o;
  o[0] = f2bf(a.x); o[1] = f2bf(a.y); o[2] = f2bf(a.z); o[3] = f2bf(a.w);
  o[4] = f2bf(b.x); o[5] = f2bf(b.y); o[6] = f2bf(b.z); o[7] = f2bf(b.w);
  *(u16x8*)(dst + (size_t)i * 8) = o;
}

// GEMM C[M,1024] = A[M,1024] * W[1024,1024]^T (both bf16, K contiguous).
// mode 0: write f32 to Cout.
// mode 1: blockIdx.z selects {Wq->Qh(+RoPE), Wk->Kh(+RoPE), Wv->Vh} head-major bf16.
// 128x128 tile, BK=64, 4 waves (each 64x64 = 4x4 frags of 16x16x32 MFMA).
__global__ __launch_bounds__(256, 2) void gemm_k(
    const unsigned short* __restrict__ A,
    const unsigned short* __restrict__ W0, const unsigned short* __restrict__ W1,
    const unsigned short* __restrict__ W2,
    const float* __restrict__ cosT, const float* __restrict__ sinT,
    unsigned short* __restrict__ Qh, unsigned short* __restrict__ Kh,
    unsigned short* __restrict__ Vh, float* __restrict__ Cout, int mode) {
  __shared__ char sm[32768];
  char* As = sm;
  char* Bs = sm + 16384;
  const int tid = threadIdx.x, lane = tid & 63, w = tid >> 6;
  const int wm = w >> 1, wn = w & 1;
  const int brow = blockIdx.y * 128;
  const int bcol = blockIdx.x * 128;
  const unsigned short* Wsel =
      (mode == 0) ? W0 : (blockIdx.z == 0 ? W0 : (blockIdx.z == 1 ? W1 : W2));

  f32x4 acc[4][4];
#pragma unroll
  for (int m = 0; m < 4; ++m)
#pragma unroll
    for (int n = 0; n < 4; ++n) acc[m][n] = (f32x4){0.f, 0.f, 0.f, 0.f};

  const char* Abase = (const char*)A + (size_t)brow * 2048;
  const char* Bbase = (const char*)Wsel + (size_t)bcol * 2048;

  for (int kt = 0; kt < 1024; kt += 64) {
    // stage A,B tiles [128 rows][64 bf16 =128B] linear LDS, source XOR-swizzled
#pragma unroll
    for (int c = 0; c < 4; ++c) {
      int Lb = w * 4096 + c * 1024;
      int L = Lb + lane * 16;
      int r = L >> 7, kb = L & 127;
      int sw = kb ^ ((r & 7) << 4);
      gld16(Abase + (size_t)r * 2048 + kt * 2 + sw, As + Lb);
      gld16(Bbase + (size_t)r * 2048 + kt * 2 + sw, Bs + Lb);
    }
    __syncthreads();
#pragma unroll
    for (int kk = 0; kk < 2; ++kk) {
      int kb = kk * 64 + (lane >> 4) * 16;
      bf16x8 af[4], bfr[4];
#pragma unroll
      for (int m = 0; m < 4; ++m) {
        int r = wm * 64 + m * 16 + (lane & 15);
        af[m] = *(const bf16x8*)(As + r * 128 + (kb ^ ((r & 7) << 4)));
      }
#pragma unroll
      for (int n = 0; n < 4; ++n) {
        int r = wn * 64 + n * 16 + (lane & 15);
        bfr[n] = *(const bf16x8*)(Bs + r * 128 + (kb ^ ((r & 7) << 4)));
      }
#pragma unroll
      for (int m = 0; m < 4; ++m)
#pragma unroll
        for (int n = 0; n < 4; ++n)
          acc[m][n] = __builtin_amdgcn_mfma_f32_16x16x32_bf16(af[m], bfr[n],
                                                              acc[m][n], 0, 0, 0);
    }
    __syncthreads();
  }

  if (mode == 0) {
#pragma unroll
    for (int m = 0; m < 4; ++m)
#pragma unroll
      for (int n = 0; n < 4; ++n)
#pragma unroll
        for (int i = 0; i < 4; ++i) {
          int row = brow + wm * 64 + m * 16 + (lane >> 4) * 4 + i;
          int col = bcol + wn * 64 + n * 16 + (lane & 15);
          Cout[(size_t)row * 1024 + col] = acc[m][n][i];
        }
  } else {
    const int z = blockIdx.z;
    unsigned short* dst = (z == 0) ? Qh : (z == 1 ? Kh : Vh);
    const int h = (bcol + wn * 64) >> 6;  // wave spans exactly one head
#pragma unroll
    for (int m = 0; m < 4; ++m)
#pragma unroll
      for (int i = 0; i < 4; ++i) {
        int row = brow + wm * 64 + m * 16 + (lane >> 4) * 4 + i;
        int b = row >> 11, s = row & 2047;
        size_t hb = ((size_t)(b * 16 + h) * 2048 + s) * 64;
        if (z == 2) {
#pragma unroll
          for (int n = 0; n < 4; ++n)
            dst[hb + n * 16 + (lane & 15)] = f2bf(acc[m][n][i]);
        } else {
          // RoPE: partner of d (<32) is d+32 = frag n+2, same lane.
#pragma unroll
          for (int n = 0; n < 2; ++n) {
            int dl = n * 16 + (lane & 15);
            float c = cosT[s * 64 + dl], sn = sinT[s * 64 + dl];
            float lo = acc[m][n][i], hi = acc[m][n + 2][i];
            dst[hb + dl] = f2bf(lo * c - hi * sn);
            dst[hb + dl + 32] = f2bf(hi * c + lo * sn);
          }
        }
      }
  }
}

// Flash attention. WG = 64 q-rows (4 waves x 16), kv tile 64.
// K staged (swizzled); V staged transposed [d][kv] with pad144+XOR layout;
// P redistributed via per-wave LDS.
__global__ __launch_bounds__(256, 2) void attn_k(
    const unsigned short* __restrict__ Q, const unsigned short* __restrict__ K,
    const unsigned short* __restrict__ V, const float* __restrict__ mask,
    unsigned short* __restrict__ O) {
  __shared__ char Ks[8192];
  __shared__ char Vs[64 * 144];
  __shared__ char Ps[4][2048];
  const int tid = threadIdx.x, lane = tid & 63, w = tid >> 6;
  const int qt = blockIdx.x, h = blockIdx.y, b = blockIdx.z;
  const size_t hb = (size_t)(b * 16 + h) * (2048 * 64);
  const int q0 = qt * 64 + w * 16;

  bf16x8 qa[2];
  {
    const char* qrow = (const char*)(Q + hb + (size_t)(q0 + (lane & 15)) * 64);
    int kb = (lane >> 4) * 16;
    qa[0] = *(const bf16x8*)(qrow + kb);
    qa[1] = *(const bf16x8*)(qrow + 64 + kb);
  }
  const float* maskb = mask + (size_t)b * 2048;

  float m_run[4], l_run[4];
  f32x4 oacc[4];
#pragma unroll
  for (int i = 0; i < 4; ++i) { m_run[i] = -1e30f; l_run[i] = 0.f; }
#pragma unroll
  for (int n = 0; n < 4; ++n) oacc[n] = (f32x4){0.f, 0.f, 0.f, 0.f};

  for (int kv0 = 0; kv0 < 2048; kv0 += 64) {
    // K tile [64][64bf16], linear dest + swizzled source
#pragma unroll
    for (int c = 0; c < 2; ++c) {
      int Lb = w * 2048 + c * 1024;
      int L = Lb + lane * 16;
      int r = L >> 7, kb = L & 127;
      gld16((const char*)(K + hb) + (size_t)(kv0 + r) * 128 + (kb ^ ((r & 7) << 4)),
            Ks + Lb);
    }
    // V transposed: Vs byte(d,kv) = d*144 + ((2kv) ^ (((d>>3)&7)<<4))
    {
      int kvp = tid >> 3, dseg = tid & 7;
      const char* vsrc =
          (const char*)(V + hb + (size_t)(kv0 + kvp * 2) * 64) + dseg * 16;
      u16x8 v0 = *(const u16x8*)(vsrc);
      u16x8 v1 = *(const u16x8*)(vsrc + 128);
#pragma unroll
      for (int j = 0; j < 8; ++j) {
        int d = dseg * 8 + j;
        unsigned pk = (unsigned)v0[j] | ((unsigned)v1[j] << 16);
        *(unsigned*)(Vs + d * 144 + ((kvp * 4) ^ (dseg << 4))) = pk;
      }
    }
    __syncthreads();

    // scores S[16q x 64kv]
    f32x4 sacc[4];
#pragma unroll
    for (int n = 0; n < 4; ++n) sacc[n] = (f32x4){0.f, 0.f, 0.f, 0.f};
#pragma unroll
    for (int kk = 0; kk < 2; ++kk) {
      int kb = kk * 64 + (lane >> 4) * 16;
#pragma unroll
      for (int n = 0; n < 4; ++n) {
        int r = n * 16 + (lane & 15);
        bf16x8 kf = *(const bf16x8*)(Ks + r * 128 + (kb ^ ((r & 7) << 4)));
        sacc[n] = __builtin_amdgcn_mfma_f32_16x16x32_bf16(qa[kk], kf, sacc[n], 0, 0, 0);
      }
    }
    float mv[4];
#pragma unroll
    for (int n = 0; n < 4; ++n) mv[n] = maskb[kv0 + n * 16 + (lane & 15)];
    float sc[4][4];
#pragma unroll
    for (int n = 0; n < 4; ++n)
#pragma unroll
      for (int i = 0; i < 4; ++i) sc[n][i] = sacc[n][i] * 0.125f + mv[n];

    float mb[4], al[4], rs[4];
#pragma unroll
    for (int i = 0; i < 4; ++i)
      mb[i] = fmaxf(fmaxf(sc[0][i], sc[1][i]), fmaxf(sc[2][i], sc[3][i]));
#pragma unroll
    for (int d = 1; d < 16; d <<= 1)
#pragma unroll
      for (int i = 0; i < 4; ++i) mb[i] = fmaxf(mb[i], __shfl_xor(mb[i], d, 64));
#pragma unroll
    for (int i = 0; i < 4; ++i) {
      float nm = fmaxf(m_run[i], mb[i]);
      al[i] = __expf(m_run[i] - nm);
      m_run[i] = nm;
    }
    float p[4][4];
#pragma unroll
    for (int n = 0; n < 4; ++n)
#pragma unroll
      for (int i = 0; i < 4; ++i) p[n][i] = __expf(sc[n][i] - m_run[i]);
#pragma unroll
    for (int i = 0; i < 4; ++i) rs[i] = p[0][i] + p[1][i] + p[2][i] + p[3][i];
#pragma unroll
    for (int d = 1; d < 16; d <<= 1)
#pragma unroll
      for (int i = 0; i < 4; ++i) rs[i] += __shfl_xor(rs[i], d, 64);
#pragma unroll
    for (int i = 0; i < 4; ++i) l_run[i] = l_run[i] * al[i] + rs[i];
#pragma unroll
    for (int n = 0; n < 4; ++n)
#pragma unroll
      for (int i = 0; i < 4; ++i) oacc[n][i] *= al[i];

    // P (D-layout) -> per-wave LDS -> A-layout
#pragma unroll
    for (int n = 0; n < 4; ++n)
#pragma unroll
      for (int i = 0; i < 4; ++i) {
        int r = (lane >> 4) * 4 + i;
        int cb = (n * 16 + (lane & 15)) * 2;
        *(unsigned short*)(Ps[w] + r * 128 + (cb ^ ((r & 7) << 4))) = f2bf(p[n][i]);
      }
    asm volatile("s_waitcnt lgkmcnt(0)" ::: "memory");
#pragma unroll
    for (int kvh = 0; kvh < 2; ++kvh) {
      int pb = kvh * 64 + (lane >> 4) * 16;
      int pr = lane & 15;
      bf16x8 pa = *(const bf16x8*)(Ps[w] + pr * 128 + (pb ^ ((pr & 7) << 4)));
#pragma unroll
      for (int n = 0; n < 4; ++n) {
        int dd = n * 16 + (lane & 15);
        int kvb = kvh * 64 + (lane >> 4) * 16;
        bf16x8 vf = *(const bf16x8*)(Vs + dd * 144 + (kvb ^ (((dd >> 3) & 7) << 4)));
        oacc[n] = __builtin_amdgcn_mfma_f32_16x16x32_bf16(pa, vf, oacc[n], 0, 0, 0);
      }
    }
    __syncthreads();
  }

#pragma unroll
  for (int i = 0; i < 4; ++i) {
    float inv = 1.0f / l_run[i];
    int row = b * 2048 + q0 + (lane >> 4) * 4 + i;
    size_t rb = (size_t)row * 1024 + h * 64;
#pragma unroll
    for (int n = 0; n < 4; ++n)
      O[rb + n * 16 + (lane & 15)] = f2bf(oacc[n][i] * inv);
  }
}

extern "C" void kernel_launch(void* const* d_in, const int* in_sizes, int n_in,
                              void* d_out, int out_size, void* d_ws, size_t ws_size,
                              hipStream_t stream) {
  const float* hidden = (const float*)d_in[0];
  const float* amask = (const float*)d_in[1];
  const float* cosT = (const float*)d_in[2];
  const float* sinT = (const float*)d_in[3];
  const float* Wq = (const float*)d_in[4];
  const float* Wk = (const float*)d_in[5];
  const float* Wv = (const float*)d_in[6];
  const float* Wo = (const float*)d_in[7];
  float* out = (float*)d_out;

  // ws layout (bf16): Xb 8M | Wq,Wk,Wv,Wo 1M each | Qh,Kh,Vh,Ob 8M each = 88 MB
  if (ws_size < (size_t)92274688) return;
  unsigned short* Xb = (unsigned short*)d_ws;
  unsigned short* Wqb = Xb + (size_t)8192 * 1024;
  unsigned short* Wkb = Wqb + (size_t)1024 * 1024;
  unsigned short* Wvb = Wkb + (size_t)1024 * 1024;
  unsigned short* Wob = Wvb + (size_t)1024 * 1024;
  unsigned short* Qh = Wob + (size_t)1024 * 1024;
  unsigned short* Kh = Qh + (size_t)8388608;
  unsigned short* Vh = Kh + (size_t)8388608;
  unsigned short* Ob = Vh + (size_t)8388608;

  cvt_bf16<<<4096, 256, 0, stream>>>(hidden, Xb, 1048576);
  cvt_bf16<<<512, 256, 0, stream>>>(Wq, Wqb, 131072);
  cvt_bf16<<<512, 256, 0, stream>>>(Wk, Wkb, 131072);
  cvt_bf16<<<512, 256, 0, stream>>>(Wv, Wvb, 131072);
  cvt_bf16<<<512, 256, 0, stream>>>(Wo, Wob, 131072);

  gemm_k<<<dim3(8, 64, 3), 256, 0, stream>>>(Xb, Wqb, Wkb, Wvb, cosT, sinT, Qh, Kh,
                                             Vh, nullptr, 1);
  attn_k<<<dim3(32, 16, 4), 256, 0, stream>>>(Qh, Kh, Vh, amask, Ob);
  gemm_k<<<dim3(8, 64, 1), 256, 0, stream>>>(Ob, Wob, Wob, Wob, cosT, sinT, nullptr,
                                             nullptr, nullptr, out, 0);
}